// Round 7
// baseline (567.683 us; speedup 1.0000x reference)
//
#include <hip/hip_runtime.h>
#include <hip/hip_bf16.h>

typedef unsigned short u16;
typedef __attribute__((ext_vector_type(8))) __bf16 bf16x8;
typedef __attribute__((ext_vector_type(4))) float f32x4;
typedef __attribute__((ext_vector_type(4))) short s16x4;

// ---------- helpers ----------
__device__ __forceinline__ u16 f2b(float f) {            // f32 -> bf16 RNE (manual)
  unsigned u = __builtin_bit_cast(unsigned, f);
  u = (u + 0x7fffu + ((u >> 16) & 1u)) >> 16;
  return (u16)u;
}

__device__ __forceinline__ u16 f2b_fast(float f) {       // native: enables v_cvt_pk_bf16_f32
  return __builtin_bit_cast(u16, (__bf16)f);
}

__device__ __forceinline__ unsigned pack2(float a, float b) {  // 2 f32 -> packed bf16x2
  return (unsigned)f2b_fast(a) | ((unsigned)f2b_fast(b) << 16);
}

__device__ __forceinline__ f32x4 mfma_bf16(uint4 a, uint4 b, f32x4 c) {
  return __builtin_amdgcn_mfma_f32_16x16x32_bf16(
      __builtin_bit_cast(bf16x8, a), __builtin_bit_cast(bf16x8, b), c, 0, 0, 0);
}

// 16x16x16 bf16 MFMA: A/B = 2 VGPRs (4 bf16), C/D = 4 f32. B-frag k=(lane>>4)*4+e.
__device__ __forceinline__ f32x4 mfma_bf16_k16(uint2 a, uint2 b, f32x4 c) {
#if __has_builtin(__builtin_amdgcn_mfma_f32_16x16x16bf16_1k)
  return __builtin_amdgcn_mfma_f32_16x16x16bf16_1k(
      __builtin_bit_cast(s16x4, a), __builtin_bit_cast(s16x4, b), c, 0, 0, 0);
#elif __has_builtin(__builtin_amdgcn_mfma_f32_16x16x16_bf16)
  return __builtin_amdgcn_mfma_f32_16x16x16_bf16(
      __builtin_bit_cast(s16x4, a), __builtin_bit_cast(s16x4, b), c, 0, 0, 0);
#else
  f32x4 d;
  asm volatile("v_mfma_f32_16x16x16_bf16 %0, %1, %2, %3"
               : "=v"(d) : "v"(a), "v"(b), "v"(c));
  return d;
#endif
}

__device__ __forceinline__ void gload_lds16(const u16* g, u16* l) {
  __builtin_amdgcn_global_load_lds(
      (const __attribute__((address_space(1))) unsigned int*)(g),
      (__attribute__((address_space(3))) unsigned int*)(l), 16, 0, 0);
}

__device__ __forceinline__ void cast8(const float* __restrict__ s, u16* __restrict__ d) {
  float4 a = *(const float4*)s;
  float4 b = *(const float4*)(s + 4);
  ushort4 lo, hi;
  lo.x = f2b(a.x); lo.y = f2b(a.y); lo.z = f2b(a.z); lo.w = f2b(a.w);
  hi.x = f2b(b.x); hi.y = f2b(b.y); hi.z = f2b(b.z); hi.w = f2b(b.w);
  *(ushort4*)d = lo;
  *(ushort4*)(d + 4) = hi;
}

// ---------- cast kernels ----------
__global__ __launch_bounds__(256) void cast_x(const float* __restrict__ src,
                                              u16* __restrict__ dst, int n) {
  int i = (blockIdx.x * 256 + threadIdx.x) * 8;
  if (i + 8 <= n) cast8(src + i, dst + i);
}

__global__ __launch_bounds__(256) void cast_w4(const float* __restrict__ w0,
                                               const float* __restrict__ w1,
                                               const float* __restrict__ w2,
                                               const float* __restrict__ w3,
                                               u16* __restrict__ dst) {
  const float* s = (blockIdx.y == 0) ? w0 : (blockIdx.y == 1) ? w1
                 : (blockIdx.y == 2) ? w2 : w3;
  u16* d = dst + (size_t)blockIdx.y * (1u << 20);
  int i = (blockIdx.x * 256 + threadIdx.x) * 8;
  cast8(s + i, d + i);
}

// mask -> additive bias {0, -3e38}
__global__ __launch_bounds__(256) void mask_bias(const int* __restrict__ msk,
                                                 float* __restrict__ mb, int n) {
  int i = blockIdx.x * 256 + threadIdx.x;
  if (i < n) mb[i] = msk[i] ? 0.0f : -3.0e38f;
}

// ---------- fused QKV GEMM: 128x128 tiles, grid (24, 64) ----------
// blockIdx.x: [0,8)=Q, [8,16)=K, [16,24)=V (stored transposed to Vt[b][h][hd][S]).
__global__ __launch_bounds__(256) void gemm_qkv(const u16* __restrict__ A,
                                                const u16* __restrict__ W,
                                                const float* __restrict__ bqp,
                                                const float* __restrict__ bkp,
                                                const float* __restrict__ bvp,
                                                u16* __restrict__ Qb,
                                                u16* __restrict__ Kb,
                                                u16* __restrict__ Vt) {
  constexpr int N = 1024, K = 1024;
  __shared__ u16 lA[128 * 32];
  __shared__ u16 lB[128 * 32];
  const int which = blockIdx.x >> 3;
  const int bx = blockIdx.x & 7;
  const u16* Bm = W + ((size_t)which << 20);
  const float* bias = (which == 0) ? bqp : (which == 1) ? bkp : bvp;

  const int tid = threadIdx.x;
  const int lane = tid & 63;
  const int w = tid >> 6;
  const int wr = w >> 1, wc = w & 1;
  const int rowBase = blockIdx.y * 128, colBase = bx * 128;
  const int lo = lane & 15, g = lane >> 4;

  f32x4 acc[4][4] = {};

  const int r0 = tid >> 2;
  const int c0 = (tid & 3) * 8;
  const u16* gA = A + (size_t)(rowBase + r0) * K + c0;
  const u16* gB = Bm + (size_t)(colBase + r0) * K + c0;
  u16* lAd = lA + w * 512;
  u16* lBd = lB + w * 512;

#pragma unroll 1
  for (int k0 = 0; k0 < K; k0 += 32) {
    gload_lds16(gA + k0, lAd);
    gload_lds16(gA + k0 + 64 * K, lAd + 2048);
    gload_lds16(gB + k0, lBd);
    gload_lds16(gB + k0 + 64 * K, lBd + 2048);
    __syncthreads();
    uint4 af[4], bf[4];
#pragma unroll
    for (int m = 0; m < 4; ++m)
      af[m] = *(const uint4*)&lA[(wr * 64 + m * 16 + lo) * 32 + g * 8];
#pragma unroll
    for (int n = 0; n < 4; ++n)
      bf[n] = *(const uint4*)&lB[(wc * 64 + n * 16 + lo) * 32 + g * 8];
#pragma unroll
    for (int m = 0; m < 4; ++m)
#pragma unroll
      for (int n = 0; n < 4; ++n)
        acc[m][n] = mfma_bf16(af[m], bf[n], acc[m][n]);
    __syncthreads();
  }

  const int cr = g * 4;
  if (which == 2) {  // V: transposed store
#pragma unroll
    for (int m = 0; m < 4; ++m)
#pragma unroll
      for (int n = 0; n < 4; ++n) {
        int i0 = rowBase + wr * 64 + m * 16 + cr;
        int jf = colBase + wc * 64 + n * 16 + lo;
        float bv = bias[jf];
        int bb = i0 >> 11, s0 = i0 & 2047;
        int hh = jf >> 6, dd = jf & 63;
        ushort4 pk;
        pk.x = f2b(acc[m][n][0] + bv);
        pk.y = f2b(acc[m][n][1] + bv);
        pk.z = f2b(acc[m][n][2] + bv);
        pk.w = f2b(acc[m][n][3] + bv);
        *(ushort4*)(Vt + ((size_t)((bb * 16 + hh) * 64 + dd)) * 2048 + s0) = pk;
      }
  } else {
    u16* dst = which ? Kb : Qb;
#pragma unroll
    for (int m = 0; m < 4; ++m)
#pragma unroll
      for (int n = 0; n < 4; ++n) {
        int gr = rowBase + wr * 64 + m * 16 + cr;
        int gc = colBase + wc * 64 + n * 16 + lo;
        float bv = bias[gc];
#pragma unroll
        for (int j = 0; j < 4; ++j)
          dst[(size_t)(gr + j) * N + gc] = f2b(acc[m][n][j] + bv);
      }
  }
}

// ---------- O-projection GEMM (f32 out) ----------
__global__ __launch_bounds__(256) void gemm_out(const u16* __restrict__ A,
                                                const u16* __restrict__ Bm,
                                                const float* __restrict__ bias,
                                                float* __restrict__ Cout) {
  constexpr int N = 1024, K = 1024;
  __shared__ u16 lA[128 * 32];
  __shared__ u16 lB[128 * 32];
  const int tid = threadIdx.x;
  const int lane = tid & 63;
  const int w = tid >> 6;
  const int wr = w >> 1, wc = w & 1;
  const int rowBase = blockIdx.y * 128, colBase = blockIdx.x * 128;
  const int lo = lane & 15, g = lane >> 4;

  f32x4 acc[4][4] = {};
  const int r0 = tid >> 2;
  const int c0 = (tid & 3) * 8;
  const u16* gA = A + (size_t)(rowBase + r0) * K + c0;
  const u16* gB = Bm + (size_t)(colBase + r0) * K + c0;
  u16* lAd = lA + w * 512;
  u16* lBd = lB + w * 512;

#pragma unroll 1
  for (int k0 = 0; k0 < K; k0 += 32) {
    gload_lds16(gA + k0, lAd);
    gload_lds16(gA + k0 + 64 * K, lAd + 2048);
    gload_lds16(gB + k0, lBd);
    gload_lds16(gB + k0 + 64 * K, lBd + 2048);
    __syncthreads();
    uint4 af[4], bf[4];
#pragma unroll
    for (int m = 0; m < 4; ++m)
      af[m] = *(const uint4*)&lA[(wr * 64 + m * 16 + lo) * 32 + g * 8];
#pragma unroll
    for (int n = 0; n < 4; ++n)
      bf[n] = *(const uint4*)&lB[(wc * 64 + n * 16 + lo) * 32 + g * 8];
#pragma unroll
    for (int m = 0; m < 4; ++m)
#pragma unroll
      for (int n = 0; n < 4; ++n)
        acc[m][n] = mfma_bf16(af[m], bf[n], acc[m][n]);
    __syncthreads();
  }

  const int cr = g * 4;
#pragma unroll
  for (int m = 0; m < 4; ++m)
#pragma unroll
    for (int n = 0; n < 4; ++n) {
      int gr = rowBase + wr * 64 + m * 16 + cr;
      int gc = colBase + wc * 64 + n * 16 + lo;
      float bv = bias[gc];
#pragma unroll
      for (int j = 0; j < 4; ++j)
        Cout[(size_t)(gr + j) * N + gc] = acc[m][n][j] + bv;
    }
}

// ---------- flash attention: swapped QK^T + lane-local k16 PV + reg prefetch ----------
// 4 independent waves/block; wave owns 32 q, KVBLK=64, 32 tiles.
// K-fragments register-double-buffered (tile t prefetches K(t+1): ~1 tile of
// latency cover). V batch-issued at tile top, consumed after softmax (~500cyc).
__global__ __launch_bounds__(256) void attn_fa(const u16* __restrict__ Qb,
                                               const u16* __restrict__ Kb,
                                               const u16* __restrict__ Vt,
                                               const float* __restrict__ mb,
                                               u16* __restrict__ Ob) {
  constexpr int S = 2048, D = 1024, H = 16, KV = 64;
  __shared__ float kbs[S];    // per-(b,h) combined ALiBi+mask bias, log2 domain
  const int tid = threadIdx.x, lane = tid & 63, w = tid >> 6;
  const int lo = lane & 15, g = lane >> 4;
  const int b = blockIdx.z, h = blockIdx.y;
  const int qt = blockIdx.x * 128 + w * 32;
  const float LOG2E = 1.4426950408889634f;
  const float slope2 = exp2f(-(float)h / 16.0f) * LOG2E;  // slope * log2(e)
  const float c1 = 0.125f * LOG2E;                        // scale * log2(e)

  {  // kbs[s] = slope2*s + maskbias[s]
    const float* mbb = mb + b * S;
    int s0 = tid * 8;
    float4 aa = *(const float4*)(mbb + s0);
    float4 bb = *(const float4*)(mbb + s0 + 4);
    kbs[s0 + 0] = fmaf(slope2, (float)(s0 + 0), aa.x);
    kbs[s0 + 1] = fmaf(slope2, (float)(s0 + 1), aa.y);
    kbs[s0 + 2] = fmaf(slope2, (float)(s0 + 2), aa.z);
    kbs[s0 + 3] = fmaf(slope2, (float)(s0 + 3), aa.w);
    kbs[s0 + 4] = fmaf(slope2, (float)(s0 + 4), bb.x);
    kbs[s0 + 5] = fmaf(slope2, (float)(s0 + 5), bb.y);
    kbs[s0 + 6] = fmaf(slope2, (float)(s0 + 6), bb.z);
    kbs[s0 + 7] = fmaf(slope2, (float)(s0 + 7), bb.w);
  }
  __syncthreads();

  // Q fragments (B-operand for swapped QK^T): lane holds Q[qt+m*16+lo][g*8..]
  uint4 aq[2][2];
#pragma unroll
  for (int m = 0; m < 2; ++m) {
    const u16* qp = Qb + (size_t)(b * S + qt + m * 16 + lo) * D + h * 64 + g * 8;
    aq[m][0] = *(const uint4*)qp;
    aq[m][1] = *(const uint4*)(qp + 32);
  }

  float mrow[2] = {-3.0e38f, -3.0e38f};
  float lrow[2] = {0.0f, 0.0f};
  f32x4 o[2][4] = {};   // o[m][dn]: O^T fragment, row d = dn*16+4g+j, col q = m*16+lo

  const u16* kbase = Kb + (size_t)b * S * D + h * 64;
  const u16* vbase = Vt + (size_t)(b * H + h) * 64 * S;

  uint4 kA[4][2], kB[4][2];   // double-buffered K fragments
#pragma unroll
  for (int n = 0; n < 4; ++n) {   // prologue: K(0) -> kA
    const u16* kr = kbase + (size_t)(n * 16 + lo) * D + g * 8;
    kA[n][0] = *(const uint4*)kr;
    kA[n][1] = *(const uint4*)(kr + 32);
  }

  auto tile = [&](uint4 (&kc)[4][2], uint4 (&kn)[4][2], int kt) {
    // ---- prefetch K(t+1) into kn (used next tile) ----
    const int ktn = (kt + KV) & (S - 1);
#pragma unroll
    for (int n = 0; n < 4; ++n) {
      const u16* kr = kbase + (size_t)(ktn + n * 16 + lo) * D + g * 8;
      kn[n][0] = *(const uint4*)kr;
      kn[n][1] = *(const uint4*)(kr + 32);
    }
    // ---- batch-issue V(t) (consumed after softmax) ----
    uint2 vv[4][4];
#pragma unroll
    for (int dn = 0; dn < 4; ++dn) {
      const u16* vr = vbase + (size_t)(dn * 16 + lo) * S + kt + g * 4;
#pragma unroll
      for (int n = 0; n < 4; ++n)
        vv[n][dn] = *(const uint2*)(vr + n * 16);
    }
    // ---- swapped QK^T on kc (loaded one tile ago) ----
    f32x4 sc[2][4];
    __builtin_amdgcn_s_setprio(1);
#pragma unroll
    for (int n = 0; n < 4; ++n)
#pragma unroll
      for (int m = 0; m < 2; ++m) {
        f32x4 z4 = {0.f, 0.f, 0.f, 0.f};
        z4 = mfma_bf16(kc[n][0], aq[m][0], z4);
        sc[m][n] = mfma_bf16(kc[n][1], aq[m][1], z4);
      }
    __builtin_amdgcn_s_setprio(0);
    // ---- bias: z = s*c1 + kbs[k], k = kt+16n+4g+j ----
#pragma unroll
    for (int n = 0; n < 4; ++n) {
      f32x4 kbv = *(const f32x4*)&kbs[kt + n * 16 + g * 4];
#pragma unroll
      for (int m = 0; m < 2; ++m)
#pragma unroll
        for (int j = 0; j < 4; ++j)
          sc[m][n][j] = fmaf(sc[m][n][j], c1, kbv[j]);
    }
    // ---- online softmax per q-column (in-lane tree + 2 shuffles) ----
#pragma unroll
    for (int m = 0; m < 2; ++m) {
      f32x4 vm = sc[m][0];
#pragma unroll
      for (int n = 1; n < 4; ++n)
#pragma unroll
        for (int j = 0; j < 4; ++j) vm[j] = fmaxf(vm[j], sc[m][n][j]);
      float pm = fmaxf(fmaxf(vm[0], vm[1]), fmaxf(vm[2], vm[3]));
      pm = fmaxf(pm, __shfl_xor(pm, 16));
      pm = fmaxf(pm, __shfl_xor(pm, 32));
      float mn = fmaxf(mrow[m], pm);
      float rs = exp2f(mrow[m] - mn);
      mrow[m] = mn;
      f32x4 vs = {0.f, 0.f, 0.f, 0.f};
#pragma unroll
      for (int n = 0; n < 4; ++n)
#pragma unroll
        for (int j = 0; j < 4; ++j) {
          float p = exp2f(sc[m][n][j] - mn);
          sc[m][n][j] = p;
          vs[j] += p;
        }
      float rsum = (vs[0] + vs[1]) + (vs[2] + vs[3]);
      rsum += __shfl_xor(rsum, 16);
      rsum += __shfl_xor(rsum, 32);
      lrow[m] = lrow[m] * rs + rsum;
#pragma unroll
      for (int dn = 0; dn < 4; ++dn)
#pragma unroll
        for (int j = 0; j < 4; ++j) o[m][dn][j] *= rs;
    }
    // ---- pack P, then PV via k16 mfma (all lane-local) ----
    uint2 pb[2][4];
#pragma unroll
    for (int m = 0; m < 2; ++m)
#pragma unroll
      for (int n = 0; n < 4; ++n) {
        pb[m][n].x = pack2(sc[m][n][0], sc[m][n][1]);
        pb[m][n].y = pack2(sc[m][n][2], sc[m][n][3]);
      }
    __builtin_amdgcn_s_setprio(1);
#pragma unroll
    for (int n = 0; n < 4; ++n)
#pragma unroll
      for (int dn = 0; dn < 4; ++dn) {
        o[0][dn] = mfma_bf16_k16(vv[n][dn], pb[0][n], o[0][dn]);
        o[1][dn] = mfma_bf16_k16(vv[n][dn], pb[1][n], o[1][dn]);
      }
    __builtin_amdgcn_s_setprio(0);
  };

#pragma unroll 1
  for (int kt = 0; kt < S; kt += 2 * KV) {
    tile(kA, kB, kt);
    tile(kB, kA, kt + KV);
  }

  // ---- normalize + store bf16 [B,S,H,hd]; ushort4 per (m,dn) ----
#pragma unroll
  for (int m = 0; m < 2; ++m) {
    float inv = 1.0f / fmaxf(lrow[m], 1e-30f);
    u16* orow = Ob + (size_t)(b * S + qt + m * 16 + lo) * D + h * 64 + g * 4;
#pragma unroll
    for (int dn = 0; dn < 4; ++dn) {
      ushort4 st;
      st.x = f2b_fast(o[m][dn][0] * inv);
      st.y = f2b_fast(o[m][dn][1] * inv);
      st.z = f2b_fast(o[m][dn][2] * inv);
      st.w = f2b_fast(o[m][dn][3] * inv);
      *(ushort4*)(orow + dn * 16) = st;
    }
  }
}

// ---------- host launcher ----------
extern "C" void kernel_launch(void* const* d_in, const int* in_sizes, int n_in,
                              void* d_out, int out_size, void* d_ws, size_t ws_size,
                              hipStream_t stream) {
  (void)in_sizes; (void)n_in; (void)out_size; (void)ws_size;
  const float* x  = (const float*)d_in[0];
  const float* Wq = (const float*)d_in[1];
  const float* bq = (const float*)d_in[2];
  const float* Wk = (const float*)d_in[3];
  const float* bk = (const float*)d_in[4];
  const float* Wv = (const float*)d_in[5];
  const float* bv = (const float*)d_in[6];
  const float* Wo = (const float*)d_in[7];
  const float* bo = (const float*)d_in[8];
  const int*  msk = (const int*)d_in[9];
  float* out = (float*)d_out;

  char* ws = (char*)d_ws;
  u16* xb  = (u16*)(ws);                       // 16MB; reused as attention output
  u16* Qb  = (u16*)(ws + ((size_t)16 << 20));
  u16* Kb  = (u16*)(ws + ((size_t)32 << 20));
  u16* Vt  = (u16*)(ws + ((size_t)48 << 20));
  u16* Wqb = (u16*)(ws + ((size_t)64 << 20));  // 4 weights, 2MB each
  float* mbf = (float*)(ws + ((size_t)72 << 20));  // mask bias, 32KB

  cast_x<<<4096, 256, 0, stream>>>(x, xb, 8192 * 1024);
  cast_w4<<<dim3(512, 4), 256, 0, stream>>>(Wq, Wk, Wv, Wo, Wqb);
  mask_bias<<<32, 256, 0, stream>>>(msk, mbf, 8192);

  gemm_qkv<<<dim3(24, 64), 256, 0, stream>>>(xb, Wqb, bq, bk, bv, Qb, Kb, Vt);

  attn_fa<<<dim3(16, 16, 4), 256, 0, stream>>>(Qb, Kb, Vt, mbf, xb /*Ob reuses xb*/);

  gemm_out<<<dim3(8, 64), 256, 0, stream>>>(xb, Wqb + (3u << 20), bo, out);
}

// Round 9
// 398.777 us; speedup vs baseline: 1.4236x; 1.4236x over previous
//
#include <hip/hip_runtime.h>
#include <hip/hip_bf16.h>

typedef unsigned short u16;
typedef __attribute__((ext_vector_type(8))) __bf16 bf16x8;
typedef __attribute__((ext_vector_type(4))) float f32x4;
typedef __attribute__((ext_vector_type(4))) short s16x4;

// ---------- helpers ----------
__device__ __forceinline__ u16 f2b(float f) {            // f32 -> bf16 RNE (manual)
  unsigned u = __builtin_bit_cast(unsigned, f);
  u = (u + 0x7fffu + ((u >> 16) & 1u)) >> 16;
  return (u16)u;
}

__device__ __forceinline__ u16 f2b_fast(float f) {       // native: enables v_cvt_pk_bf16_f32
  return __builtin_bit_cast(u16, (__bf16)f);
}

__device__ __forceinline__ unsigned pack2(float a, float b) {  // 2 f32 -> packed bf16x2
  return (unsigned)f2b_fast(a) | ((unsigned)f2b_fast(b) << 16);
}

__device__ __forceinline__ f32x4 mfma_bf16(uint4 a, uint4 b, f32x4 c) {
  return __builtin_amdgcn_mfma_f32_16x16x32_bf16(
      __builtin_bit_cast(bf16x8, a), __builtin_bit_cast(bf16x8, b), c, 0, 0, 0);
}

// 16x16x16 bf16 MFMA: A/B = 2 VGPRs (4 bf16), C/D = 4 f32. B-frag k=(lane>>4)*4+e.
__device__ __forceinline__ f32x4 mfma_bf16_k16(uint2 a, uint2 b, f32x4 c) {
#if __has_builtin(__builtin_amdgcn_mfma_f32_16x16x16bf16_1k)
  return __builtin_amdgcn_mfma_f32_16x16x16bf16_1k(
      __builtin_bit_cast(s16x4, a), __builtin_bit_cast(s16x4, b), c, 0, 0, 0);
#elif __has_builtin(__builtin_amdgcn_mfma_f32_16x16x16_bf16)
  return __builtin_amdgcn_mfma_f32_16x16x16_bf16(
      __builtin_bit_cast(s16x4, a), __builtin_bit_cast(s16x4, b), c, 0, 0, 0);
#else
  f32x4 d;
  asm volatile("v_mfma_f32_16x16x16_bf16 %0, %1, %2, %3"
               : "=v"(d) : "v"(a), "v"(b), "v"(c));
  return d;
#endif
}

__device__ __forceinline__ void gload_lds16(const u16* g, u16* l) {
  __builtin_amdgcn_global_load_lds(
      (const __attribute__((address_space(1))) unsigned int*)(g),
      (__attribute__((address_space(3))) unsigned int*)(l), 16, 0, 0);
}

__device__ __forceinline__ void cast8(const float* __restrict__ s, u16* __restrict__ d) {
  float4 a = *(const float4*)s;
  float4 b = *(const float4*)(s + 4);
  ushort4 lo, hi;
  lo.x = f2b(a.x); lo.y = f2b(a.y); lo.z = f2b(a.z); lo.w = f2b(a.w);
  hi.x = f2b(b.x); hi.y = f2b(b.y); hi.z = f2b(b.z); hi.w = f2b(b.w);
  *(ushort4*)d = lo;
  *(ushort4*)(d + 4) = hi;
}

// ---------- cast kernels ----------
__global__ __launch_bounds__(256) void cast_x(const float* __restrict__ src,
                                              u16* __restrict__ dst, int n) {
  int i = (blockIdx.x * 256 + threadIdx.x) * 8;
  if (i + 8 <= n) cast8(src + i, dst + i);
}

__global__ __launch_bounds__(256) void cast_w4(const float* __restrict__ w0,
                                               const float* __restrict__ w1,
                                               const float* __restrict__ w2,
                                               const float* __restrict__ w3,
                                               u16* __restrict__ dst) {
  const float* s = (blockIdx.y == 0) ? w0 : (blockIdx.y == 1) ? w1
                 : (blockIdx.y == 2) ? w2 : w3;
  u16* d = dst + (size_t)blockIdx.y * (1u << 20);
  int i = (blockIdx.x * 256 + threadIdx.x) * 8;
  cast8(s + i, d + i);
}

// mask -> additive bias {0, -3e38}
__global__ __launch_bounds__(256) void mask_bias(const int* __restrict__ msk,
                                                 float* __restrict__ mb, int n) {
  int i = blockIdx.x * 256 + threadIdx.x;
  if (i < n) mb[i] = msk[i] ? 0.0f : -3.0e38f;
}

// ---------- fused QKV GEMM: 128x128 tiles, grid (24, 64) ----------
__global__ __launch_bounds__(256) void gemm_qkv(const u16* __restrict__ A,
                                                const u16* __restrict__ W,
                                                const float* __restrict__ bqp,
                                                const float* __restrict__ bkp,
                                                const float* __restrict__ bvp,
                                                u16* __restrict__ Qb,
                                                u16* __restrict__ Kb,
                                                u16* __restrict__ Vt) {
  constexpr int N = 1024, K = 1024;
  __shared__ u16 lA[128 * 32];
  __shared__ u16 lB[128 * 32];
  const int which = blockIdx.x >> 3;
  const int bx = blockIdx.x & 7;
  const u16* Bm = W + ((size_t)which << 20);
  const float* bias = (which == 0) ? bqp : (which == 1) ? bkp : bvp;

  const int tid = threadIdx.x;
  const int lane = tid & 63;
  const int w = tid >> 6;
  const int wr = w >> 1, wc = w & 1;
  const int rowBase = blockIdx.y * 128, colBase = bx * 128;
  const int lo = lane & 15, g = lane >> 4;

  f32x4 acc[4][4] = {};

  const int r0 = tid >> 2;
  const int c0 = (tid & 3) * 8;
  const u16* gA = A + (size_t)(rowBase + r0) * K + c0;
  const u16* gB = Bm + (size_t)(colBase + r0) * K + c0;
  u16* lAd = lA + w * 512;
  u16* lBd = lB + w * 512;

#pragma unroll 1
  for (int k0 = 0; k0 < K; k0 += 32) {
    gload_lds16(gA + k0, lAd);
    gload_lds16(gA + k0 + 64 * K, lAd + 2048);
    gload_lds16(gB + k0, lBd);
    gload_lds16(gB + k0 + 64 * K, lBd + 2048);
    __syncthreads();
    uint4 af[4], bf[4];
#pragma unroll
    for (int m = 0; m < 4; ++m)
      af[m] = *(const uint4*)&lA[(wr * 64 + m * 16 + lo) * 32 + g * 8];
#pragma unroll
    for (int n = 0; n < 4; ++n)
      bf[n] = *(const uint4*)&lB[(wc * 64 + n * 16 + lo) * 32 + g * 8];
#pragma unroll
    for (int m = 0; m < 4; ++m)
#pragma unroll
      for (int n = 0; n < 4; ++n)
        acc[m][n] = mfma_bf16(af[m], bf[n], acc[m][n]);
    __syncthreads();
  }

  const int cr = g * 4;
  if (which == 2) {  // V: transposed store -> Vt[b][h][hd][S]
#pragma unroll
    for (int m = 0; m < 4; ++m)
#pragma unroll
      for (int n = 0; n < 4; ++n) {
        int i0 = rowBase + wr * 64 + m * 16 + cr;
        int jf = colBase + wc * 64 + n * 16 + lo;
        float bv = bias[jf];
        int bb = i0 >> 11, s0 = i0 & 2047;
        int hh = jf >> 6, dd = jf & 63;
        ushort4 pk;
        pk.x = f2b(acc[m][n][0] + bv);
        pk.y = f2b(acc[m][n][1] + bv);
        pk.z = f2b(acc[m][n][2] + bv);
        pk.w = f2b(acc[m][n][3] + bv);
        *(ushort4*)(Vt + ((size_t)((bb * 16 + hh) * 64 + dd)) * 2048 + s0) = pk;
      }
  } else {
    u16* dst = which ? Kb : Qb;
#pragma unroll
    for (int m = 0; m < 4; ++m)
#pragma unroll
      for (int n = 0; n < 4; ++n) {
        int gr = rowBase + wr * 64 + m * 16 + cr;
        int gc = colBase + wc * 64 + n * 16 + lo;
        float bv = bias[gc];
#pragma unroll
        for (int j = 0; j < 4; ++j)
          dst[(size_t)(gr + j) * N + gc] = f2b(acc[m][n][j] + bv);
      }
  }
}

// ---------- O-projection GEMM (f32 out) ----------
__global__ __launch_bounds__(256) void gemm_out(const u16* __restrict__ A,
                                                const u16* __restrict__ Bm,
                                                const float* __restrict__ bias,
                                                float* __restrict__ Cout) {
  constexpr int N = 1024, K = 1024;
  __shared__ u16 lA[128 * 32];
  __shared__ u16 lB[128 * 32];
  const int tid = threadIdx.x;
  const int lane = tid & 63;
  const int w = tid >> 6;
  const int wr = w >> 1, wc = w & 1;
  const int rowBase = blockIdx.y * 128, colBase = blockIdx.x * 128;
  const int lo = lane & 15, g = lane >> 4;

  f32x4 acc[4][4] = {};
  const int r0 = tid >> 2;
  const int c0 = (tid & 3) * 8;
  const u16* gA = A + (size_t)(rowBase + r0) * K + c0;
  const u16* gB = Bm + (size_t)(colBase + r0) * K + c0;
  u16* lAd = lA + w * 512;
  u16* lBd = lB + w * 512;

#pragma unroll 1
  for (int k0 = 0; k0 < K; k0 += 32) {
    gload_lds16(gA + k0, lAd);
    gload_lds16(gA + k0 + 64 * K, lAd + 2048);
    gload_lds16(gB + k0, lBd);
    gload_lds16(gB + k0 + 64 * K, lBd + 2048);
    __syncthreads();
    uint4 af[4], bf[4];
#pragma unroll
    for (int m = 0; m < 4; ++m)
      af[m] = *(const uint4*)&lA[(wr * 64 + m * 16 + lo) * 32 + g * 8];
#pragma unroll
    for (int n = 0; n < 4; ++n)
      bf[n] = *(const uint4*)&lB[(wc * 64 + n * 16 + lo) * 32 + g * 8];
#pragma unroll
    for (int m = 0; m < 4; ++m)
#pragma unroll
      for (int n = 0; n < 4; ++n)
        acc[m][n] = mfma_bf16(af[m], bf[n], acc[m][n]);
    __syncthreads();
  }

  const int cr = g * 4;
#pragma unroll
  for (int m = 0; m < 4; ++m)
#pragma unroll
    for (int n = 0; n < 4; ++n) {
      int gr = rowBase + wr * 64 + m * 16 + cr;
      int gc = colBase + wc * 64 + n * 16 + lo;
      float bv = bias[gc];
#pragma unroll
      for (int j = 0; j < 4; ++j)
        Cout[(size_t)(gr + j) * N + gc] = acc[m][n][j] + bv;
    }
}

// ---------- flash attention: block-shared LDS K/V staging + swapped QK^T + k16 PV ----
// 4 waves/block share (b,h): K/V staged ONCE per block into LDS (4x traffic cut).
// 2-phase pipeline with counted vmcnt + raw s_barrier (stage(t+1) stays in
// flight across compute(t)). XOR swizzle (chunk ^= row&7) applied on the
// global SOURCE at stage time (linear LDS dest) and on every ds_read.
__global__ __launch_bounds__(256) void attn_fa(const u16* __restrict__ Qb,
                                               const u16* __restrict__ Kb,
                                               const u16* __restrict__ Vt,
                                               const float* __restrict__ mb,
                                               u16* __restrict__ Ob) {
  constexpr int S = 2048, D = 1024, H = 16, KV = 64, NT = S / KV;
  __shared__ float kbs[S];          // 8KB: ALiBi+mask bias (log2 domain)
  __shared__ u16 lK[2][64 * 64];    // 2 x 8KB: K tile, 64 rows x 64 halves, swizzled
  __shared__ u16 lV[2][64 * 64];    // 2 x 8KB: V^T tile, 64 d-rows x 64 halves
  const int tid = threadIdx.x, lane = tid & 63, w = tid >> 6;
  const int lo = lane & 15, g = lane >> 4;
  const int b = blockIdx.z, h = blockIdx.y;
  const int qt = blockIdx.x * 128 + w * 32;
  const float LOG2E = 1.4426950408889634f;
  const float slope2 = exp2f(-(float)h / 16.0f) * LOG2E;  // slope * log2(e)
  const float c1 = 0.125f * LOG2E;                        // scale * log2(e)

  {  // kbs[s] = slope2*s + maskbias[s]
    const float* mbb = mb + b * S;
    int s0 = tid * 8;
    float4 aa = *(const float4*)(mbb + s0);
    float4 bb = *(const float4*)(mbb + s0 + 4);
    kbs[s0 + 0] = fmaf(slope2, (float)(s0 + 0), aa.x);
    kbs[s0 + 1] = fmaf(slope2, (float)(s0 + 1), aa.y);
    kbs[s0 + 2] = fmaf(slope2, (float)(s0 + 2), aa.z);
    kbs[s0 + 3] = fmaf(slope2, (float)(s0 + 3), aa.w);
    kbs[s0 + 4] = fmaf(slope2, (float)(s0 + 4), bb.x);
    kbs[s0 + 5] = fmaf(slope2, (float)(s0 + 5), bb.y);
    kbs[s0 + 6] = fmaf(slope2, (float)(s0 + 6), bb.z);
    kbs[s0 + 7] = fmaf(slope2, (float)(s0 + 7), bb.w);
  }

  // Q fragments (B-operand for swapped QK^T): lane holds Q[qt+m*16+lo][g*8..]
  uint4 aq[2][2];
#pragma unroll
  for (int m = 0; m < 2; ++m) {
    const u16* qp = Qb + (size_t)(b * S + qt + m * 16 + lo) * D + h * 64 + g * 8;
    aq[m][0] = *(const uint4*)qp;
    aq[m][1] = *(const uint4*)(qp + 32);
  }

  float mrow[2] = {-3.0e38f, -3.0e38f};
  float lrow[2] = {0.0f, 0.0f};
  f32x4 o[2][4] = {};   // o[m][dn]: O^T fragment, row d = dn*16+4g+j, col q = m*16+lo

  const u16* kbase = Kb + (size_t)b * S * D + h * 64;
  const u16* vbase = Vt + (size_t)(b * H + h) * 64 * S;

  // stage K/V tile kt into buf: 64 rows x 8 chunks(16B); thread covers chunk
  // linear idx i = j*256+tid; source chunk XOR-swizzled so LDS(row,c)=G(row,c^row&7)
  auto stage = [&](int buf, int kt) {
#pragma unroll
    for (int j = 0; j < 2; ++j) {
      int i = j * 256 + tid;
      int row = i >> 3, c = i & 7;
      int sw = row & 7;
      u16* dK = &lK[buf][(j * 4 + w) * 512];
      u16* dV = &lV[buf][(j * 4 + w) * 512];
      gload_lds16(kbase + (size_t)(kt + row) * D + ((c ^ sw) * 8), dK);
      gload_lds16(vbase + (size_t)row * S + kt + ((c ^ sw) * 8), dV);
    }
  };

  __syncthreads();          // kbs ready (also before any staging)
  stage(0, 0);              // prologue

#pragma unroll 1
  for (int t = 0; t < NT; ++t) {
    const int buf = t & 1;
    const int kt = t * KV;
    if (t + 1 < NT) {
      stage(buf ^ 1, kt + KV);
      asm volatile("s_waitcnt vmcnt(4)" ::: "memory");   // stage(t) landed; t+1 in flight
    } else {
      asm volatile("s_waitcnt vmcnt(0)" ::: "memory");
    }
    __builtin_amdgcn_s_barrier();          // all waves' stage(t) visible
    __builtin_amdgcn_sched_barrier(0);

    const u16* lk = lK[buf];
    const u16* lv = lV[buf];

    // ---- swapped QK^T: sc[m][n] row=k-local(4g+j), col=q(lo) ----
    f32x4 sc[2][4];
    __builtin_amdgcn_s_setprio(1);
#pragma unroll
    for (int n = 0; n < 4; ++n) {
      int row = n * 16 + lo, sw = row & 7;
      uint4 k0 = *(const uint4*)&lk[row * 64 + ((g ^ sw) * 8)];
      uint4 k1 = *(const uint4*)&lk[row * 64 + (((g + 4) ^ sw) * 8)];
#pragma unroll
      for (int m = 0; m < 2; ++m) {
        f32x4 z4 = {0.f, 0.f, 0.f, 0.f};
        z4 = mfma_bf16(k0, aq[m][0], z4);
        sc[m][n] = mfma_bf16(k1, aq[m][1], z4);
      }
    }
    __builtin_amdgcn_s_setprio(0);

    // ---- bias: z = s*c1 + kbs[k], k = kt+16n+4g+j ----
#pragma unroll
    for (int n = 0; n < 4; ++n) {
      f32x4 kbv = *(const f32x4*)&kbs[kt + n * 16 + g * 4];
#pragma unroll
      for (int m = 0; m < 2; ++m)
#pragma unroll
        for (int j = 0; j < 4; ++j)
          sc[m][n][j] = fmaf(sc[m][n][j], c1, kbv[j]);
    }
    // ---- online softmax per q-column (in-lane tree + 2 shuffles) ----
#pragma unroll
    for (int m = 0; m < 2; ++m) {
      f32x4 vm = sc[m][0];
#pragma unroll
      for (int n = 1; n < 4; ++n)
#pragma unroll
        for (int j = 0; j < 4; ++j) vm[j] = fmaxf(vm[j], sc[m][n][j]);
      float pm = fmaxf(fmaxf(vm[0], vm[1]), fmaxf(vm[2], vm[3]));
      pm = fmaxf(pm, __shfl_xor(pm, 16));
      pm = fmaxf(pm, __shfl_xor(pm, 32));
      float mn = fmaxf(mrow[m], pm);
      float rs = exp2f(mrow[m] - mn);
      mrow[m] = mn;
      f32x4 vs = {0.f, 0.f, 0.f, 0.f};
#pragma unroll
      for (int n = 0; n < 4; ++n)
#pragma unroll
        for (int j = 0; j < 4; ++j) {
          float p = exp2f(sc[m][n][j] - mn);
          sc[m][n][j] = p;
          vs[j] += p;
        }
      float rsum = (vs[0] + vs[1]) + (vs[2] + vs[3]);
      rsum += __shfl_xor(rsum, 16);
      rsum += __shfl_xor(rsum, 32);
      lrow[m] = lrow[m] * rs + rsum;
#pragma unroll
      for (int dn = 0; dn < 4; ++dn)
#pragma unroll
        for (int j = 0; j < 4; ++j) o[m][dn][j] *= rs;
    }
    // ---- PV via k16 mfma: P lane-local; V from LDS (swizzled 8B reads) ----
    __builtin_amdgcn_s_setprio(1);
#pragma unroll
    for (int n = 0; n < 4; ++n) {
      uint2 pb0, pb1;
      pb0.x = pack2(sc[0][n][0], sc[0][n][1]);
      pb0.y = pack2(sc[0][n][2], sc[0][n][3]);
      pb1.x = pack2(sc[1][n][0], sc[1][n][1]);
      pb1.y = pack2(sc[1][n][2], sc[1][n][3]);
      int cw = 2 * n + (g >> 1);
      int off8 = (g & 1) * 4;
#pragma unroll
      for (int dn = 0; dn < 4; ++dn) {
        int row = dn * 16 + lo, sw = row & 7;
        uint2 va = *(const uint2*)&lv[row * 64 + ((cw ^ sw) * 8) + off8];
        o[0][dn] = mfma_bf16_k16(va, pb0, o[0][dn]);
        o[1][dn] = mfma_bf16_k16(va, pb1, o[1][dn]);
      }
    }
    __builtin_amdgcn_s_setprio(0);

    __builtin_amdgcn_sched_barrier(0);
    __builtin_amdgcn_s_barrier();          // all waves done reading buf
  }

  // ---- normalize + store bf16 [B,S,H,hd]; ushort4 per (m,dn) ----
#pragma unroll
  for (int m = 0; m < 2; ++m) {
    float inv = 1.0f / fmaxf(lrow[m], 1e-30f);
    u16* orow = Ob + (size_t)(b * S + qt + m * 16 + lo) * D + h * 64 + g * 4;
#pragma unroll
    for (int dn = 0; dn < 4; ++dn) {
      ushort4 st;
      st.x = f2b_fast(o[m][dn][0] * inv);
      st.y = f2b_fast(o[m][dn][1] * inv);
      st.z = f2b_fast(o[m][dn][2] * inv);
      st.w = f2b_fast(o[m][dn][3] * inv);
      *(ushort4*)(orow + dn * 16) = st;
    }
  }
}

// ---------- host launcher ----------
extern "C" void kernel_launch(void* const* d_in, const int* in_sizes, int n_in,
                              void* d_out, int out_size, void* d_ws, size_t ws_size,
                              hipStream_t stream) {
  (void)in_sizes; (void)n_in; (void)out_size; (void)ws_size;
  const float* x  = (const float*)d_in[0];
  const float* Wq = (const float*)d_in[1];
  const float* bq = (const float*)d_in[2];
  const float* Wk = (const float*)d_in[3];
  const float* bk = (const float*)d_in[4];
  const float* Wv = (const float*)d_in[5];
  const float* bv = (const float*)d_in[6];
  const float* Wo = (const float*)d_in[7];
  const float* bo = (const float*)d_in[8];
  const int*  msk = (const int*)d_in[9];
  float* out = (float*)d_out;

  char* ws = (char*)d_ws;
  u16* xb  = (u16*)(ws);                       // 16MB; reused as attention output
  u16* Qb  = (u16*)(ws + ((size_t)16 << 20));
  u16* Kb  = (u16*)(ws + ((size_t)32 << 20));
  u16* Vt  = (u16*)(ws + ((size_t)48 << 20));
  u16* Wqb = (u16*)(ws + ((size_t)64 << 20));  // 4 weights, 2MB each
  float* mbf = (float*)(ws + ((size_t)72 << 20));  // mask bias, 32KB

  cast_x<<<4096, 256, 0, stream>>>(x, xb, 8192 * 1024);
  cast_w4<<<dim3(512, 4), 256, 0, stream>>>(Wq, Wk, Wv, Wo, Wqb);
  mask_bias<<<32, 256, 0, stream>>>(msk, mbf, 8192);

  gemm_qkv<<<dim3(24, 64), 256, 0, stream>>>(xb, Wqb, bq, bk, bv, Qb, Kb, Vt);

  attn_fa<<<dim3(16, 16, 4), 256, 0, stream>>>(Qb, Kb, Vt, mbf, xb /*Ob reuses xb*/);

  gemm_out<<<dim3(8, 64), 256, 0, stream>>>(xb, Wqb + (3u << 20), bo, out);
}

// Round 11
// 306.067 us; speedup vs baseline: 1.8548x; 1.3029x over previous
//
#include <hip/hip_runtime.h>
#include <hip/hip_bf16.h>

typedef unsigned short u16;
typedef __attribute__((ext_vector_type(8))) __bf16 bf16x8;
typedef __attribute__((ext_vector_type(4))) float f32x4;
typedef __attribute__((ext_vector_type(4))) short s16x4;

// ---------- helpers ----------
__device__ __forceinline__ u16 f2b(float f) {            // f32 -> bf16 RNE (manual)
  unsigned u = __builtin_bit_cast(unsigned, f);
  u = (u + 0x7fffu + ((u >> 16) & 1u)) >> 16;
  return (u16)u;
}

__device__ __forceinline__ u16 f2b_fast(float f) {       // native: enables v_cvt_pk_bf16_f32
  return __builtin_bit_cast(u16, (__bf16)f);
}

__device__ __forceinline__ unsigned pack2(float a, float b) {  // 2 f32 -> packed bf16x2
  return (unsigned)f2b_fast(a) | ((unsigned)f2b_fast(b) << 16);
}

__device__ __forceinline__ f32x4 mfma_bf16(uint4 a, uint4 b, f32x4 c) {
  return __builtin_amdgcn_mfma_f32_16x16x32_bf16(
      __builtin_bit_cast(bf16x8, a), __builtin_bit_cast(bf16x8, b), c, 0, 0, 0);
}

// 16x16x16 bf16 MFMA: A/B = 2 VGPRs (4 bf16), C/D = 4 f32. B-frag k=(lane>>4)*4+e.
__device__ __forceinline__ f32x4 mfma_bf16_k16(uint2 a, uint2 b, f32x4 c) {
#if __has_builtin(__builtin_amdgcn_mfma_f32_16x16x16bf16_1k)
  return __builtin_amdgcn_mfma_f32_16x16x16bf16_1k(
      __builtin_bit_cast(s16x4, a), __builtin_bit_cast(s16x4, b), c, 0, 0, 0);
#elif __has_builtin(__builtin_amdgcn_mfma_f32_16x16x16_bf16)
  return __builtin_amdgcn_mfma_f32_16x16x16_bf16(
      __builtin_bit_cast(s16x4, a), __builtin_bit_cast(s16x4, b), c, 0, 0, 0);
#else
  f32x4 d;
  asm volatile("v_mfma_f32_16x16x16_bf16 %0, %1, %2, %3"
               : "=v"(d) : "v"(a), "v"(b), "v"(c));
  return d;
#endif
}

__device__ __forceinline__ void gload_lds16(const u16* g, u16* l) {
  __builtin_amdgcn_global_load_lds(
      (const __attribute__((address_space(1))) unsigned int*)(g),
      (__attribute__((address_space(3))) unsigned int*)(l), 16, 0, 0);
}

__device__ __forceinline__ void cast8(const float* __restrict__ s, u16* __restrict__ d) {
  float4 a = *(const float4*)s;
  float4 b = *(const float4*)(s + 4);
  ushort4 lo, hi;
  lo.x = f2b(a.x); lo.y = f2b(a.y); lo.z = f2b(a.z); lo.w = f2b(a.w);
  hi.x = f2b(b.x); hi.y = f2b(b.y); hi.z = f2b(b.z); hi.w = f2b(b.w);
  *(ushort4*)d = lo;
  *(ushort4*)(d + 4) = hi;
}

// ---------- cast kernels ----------
__global__ __launch_bounds__(256) void cast_x(const float* __restrict__ src,
                                              u16* __restrict__ dst, int n) {
  int i = (blockIdx.x * 256 + threadIdx.x) * 8;
  if (i + 8 <= n) cast8(src + i, dst + i);
}

__global__ __launch_bounds__(256) void cast_w4(const float* __restrict__ w0,
                                               const float* __restrict__ w1,
                                               const float* __restrict__ w2,
                                               const float* __restrict__ w3,
                                               u16* __restrict__ dst) {
  const float* s = (blockIdx.y == 0) ? w0 : (blockIdx.y == 1) ? w1
                 : (blockIdx.y == 2) ? w2 : w3;
  u16* d = dst + (size_t)blockIdx.y * (1u << 20);
  int i = (blockIdx.x * 256 + threadIdx.x) * 8;
  cast8(s + i, d + i);
}

// mask -> additive bias {0, -3e38}
__global__ __launch_bounds__(256) void mask_bias(const int* __restrict__ msk,
                                                 float* __restrict__ mb, int n) {
  int i = blockIdx.x * 256 + threadIdx.x;
  if (i < n) mb[i] = msk[i] ? 0.0f : -3.0e38f;
}

// ---------- fused QKV GEMM: 128x128 tiles, grid (24, 64) ----------
__global__ __launch_bounds__(256) void gemm_qkv(const u16* __restrict__ A,
                                                const u16* __restrict__ W,
                                                const float* __restrict__ bqp,
                                                const float* __restrict__ bkp,
                                                const float* __restrict__ bvp,
                                                u16* __restrict__ Qb,
                                                u16* __restrict__ Kb,
                                                u16* __restrict__ Vt) {
  constexpr int N = 1024, K = 1024;
  __shared__ u16 lA[128 * 32];
  __shared__ u16 lB[128 * 32];
  const int which = blockIdx.x >> 3;
  const int bx = blockIdx.x & 7;
  const u16* Bm = W + ((size_t)which << 20);
  const float* bias = (which == 0) ? bqp : (which == 1) ? bkp : bvp;

  const int tid = threadIdx.x;
  const int lane = tid & 63;
  const int w = tid >> 6;
  const int wr = w >> 1, wc = w & 1;
  const int rowBase = blockIdx.y * 128, colBase = bx * 128;
  const int lo = lane & 15, g = lane >> 4;

  f32x4 acc[4][4] = {};

  const int r0 = tid >> 2;
  const int c0 = (tid & 3) * 8;
  const u16* gA = A + (size_t)(rowBase + r0) * K + c0;
  const u16* gB = Bm + (size_t)(colBase + r0) * K + c0;
  u16* lAd = lA + w * 512;
  u16* lBd = lB + w * 512;

#pragma unroll 1
  for (int k0 = 0; k0 < K; k0 += 32) {
    gload_lds16(gA + k0, lAd);
    gload_lds16(gA + k0 + 64 * K, lAd + 2048);
    gload_lds16(gB + k0, lBd);
    gload_lds16(gB + k0 + 64 * K, lBd + 2048);
    __syncthreads();
    uint4 af[4], bf[4];
#pragma unroll
    for (int m = 0; m < 4; ++m)
      af[m] = *(const uint4*)&lA[(wr * 64 + m * 16 + lo) * 32 + g * 8];
#pragma unroll
    for (int n = 0; n < 4; ++n)
      bf[n] = *(const uint4*)&lB[(wc * 64 + n * 16 + lo) * 32 + g * 8];
#pragma unroll
    for (int m = 0; m < 4; ++m)
#pragma unroll
      for (int n = 0; n < 4; ++n)
        acc[m][n] = mfma_bf16(af[m], bf[n], acc[m][n]);
    __syncthreads();
  }

  const int cr = g * 4;
  if (which == 2) {  // V: transposed store -> Vt[b][h][hd][S]
#pragma unroll
    for (int m = 0; m < 4; ++m)
#pragma unroll
      for (int n = 0; n < 4; ++n) {
        int i0 = rowBase + wr * 64 + m * 16 + cr;
        int jf = colBase + wc * 64 + n * 16 + lo;
        float bv = bias[jf];
        int bb = i0 >> 11, s0 = i0 & 2047;
        int hh = jf >> 6, dd = jf & 63;
        ushort4 pk;
        pk.x = f2b(acc[m][n][0] + bv);
        pk.y = f2b(acc[m][n][1] + bv);
        pk.z = f2b(acc[m][n][2] + bv);
        pk.w = f2b(acc[m][n][3] + bv);
        *(ushort4*)(Vt + ((size_t)((bb * 16 + hh) * 64 + dd)) * 2048 + s0) = pk;
      }
  } else {
    u16* dst = which ? Kb : Qb;
#pragma unroll
    for (int m = 0; m < 4; ++m)
#pragma unroll
      for (int n = 0; n < 4; ++n) {
        int gr = rowBase + wr * 64 + m * 16 + cr;
        int gc = colBase + wc * 64 + n * 16 + lo;
        float bv = bias[gc];
#pragma unroll
        for (int j = 0; j < 4; ++j)
          dst[(size_t)(gr + j) * N + gc] = f2b(acc[m][n][j] + bv);
      }
  }
}

// ---------- O-projection GEMM (f32 out) ----------
__global__ __launch_bounds__(256) void gemm_out(const u16* __restrict__ A,
                                                const u16* __restrict__ Bm,
                                                const float* __restrict__ bias,
                                                float* __restrict__ Cout) {
  constexpr int N = 1024, K = 1024;
  __shared__ u16 lA[128 * 32];
  __shared__ u16 lB[128 * 32];
  const int tid = threadIdx.x;
  const int lane = tid & 63;
  const int w = tid >> 6;
  const int wr = w >> 1, wc = w & 1;
  const int rowBase = blockIdx.y * 128, colBase = blockIdx.x * 128;
  const int lo = lane & 15, g = lane >> 4;

  f32x4 acc[4][4] = {};
  const int r0 = tid >> 2;
  const int c0 = (tid & 3) * 8;
  const u16* gA = A + (size_t)(rowBase + r0) * K + c0;
  const u16* gB = Bm + (size_t)(colBase + r0) * K + c0;
  u16* lAd = lA + w * 512;
  u16* lBd = lB + w * 512;

#pragma unroll 1
  for (int k0 = 0; k0 < K; k0 += 32) {
    gload_lds16(gA + k0, lAd);
    gload_lds16(gA + k0 + 64 * K, lAd + 2048);
    gload_lds16(gB + k0, lBd);
    gload_lds16(gB + k0 + 64 * K, lBd + 2048);
    __syncthreads();
    uint4 af[4], bf[4];
#pragma unroll
    for (int m = 0; m < 4; ++m)
      af[m] = *(const uint4*)&lA[(wr * 64 + m * 16 + lo) * 32 + g * 8];
#pragma unroll
    for (int n = 0; n < 4; ++n)
      bf[n] = *(const uint4*)&lB[(wc * 64 + n * 16 + lo) * 32 + g * 8];
#pragma unroll
    for (int m = 0; m < 4; ++m)
#pragma unroll
      for (int n = 0; n < 4; ++n)
        acc[m][n] = mfma_bf16(af[m], bf[n], acc[m][n]);
    __syncthreads();
  }

  const int cr = g * 4;
#pragma unroll
  for (int m = 0; m < 4; ++m)
#pragma unroll
    for (int n = 0; n < 4; ++n) {
      int gr = rowBase + wr * 64 + m * 16 + cr;
      int gc = colBase + wc * 64 + n * 16 + lo;
      float bv = bias[gc];
#pragma unroll
      for (int j = 0; j < 4; ++j)
        Cout[(size_t)(gr + j) * N + gc] = acc[m][n][j] + bv;
    }
}

// ---------- flash attention: LDS-staged K/V + swapped QK^T + k16 PV + tile skip ----
// Tiles processed in DESCENDING k order. ALiBi bias (log2 domain) grows by
// slope2*64 >= 48 per tile, so after the first (highest-k) tile the running
// max dominates; a tile with __all(pm <= mrow - 25) contributes < 2^-19 of
// the row sum -> skip exp/sum/rescale/PV (rigorous, data-driven, mask-safe).
__global__ __launch_bounds__(256) void attn_fa(const u16* __restrict__ Qb,
                                               const u16* __restrict__ Kb,
                                               const u16* __restrict__ Vt,
                                               const float* __restrict__ mb,
                                               u16* __restrict__ Ob) {
  constexpr int S = 2048, D = 1024, H = 16, KV = 64, NT = S / KV;
  __shared__ float kbs[S];          // 8KB: ALiBi+mask bias (log2 domain)
  __shared__ u16 lK[2][64 * 64];    // 2 x 8KB: K tile, swizzled
  __shared__ u16 lV[2][64 * 64];    // 2 x 8KB: V^T tile, swizzled
  const int tid = threadIdx.x, lane = tid & 63, w = tid >> 6;
  const int lo = lane & 15, g = lane >> 4;
  const int b = blockIdx.z, h = blockIdx.y;
  const int qt = blockIdx.x * 128 + w * 32;
  const float LOG2E = 1.4426950408889634f;
  const float slope2 = exp2f(-(float)h / 16.0f) * LOG2E;  // slope * log2(e)
  const float c1 = 0.125f * LOG2E;                        // scale * log2(e)

  {  // kbs[s] = slope2*s + maskbias[s]
    const float* mbb = mb + b * S;
    int s0 = tid * 8;
    float4 aa = *(const float4*)(mbb + s0);
    float4 bb = *(const float4*)(mbb + s0 + 4);
    kbs[s0 + 0] = fmaf(slope2, (float)(s0 + 0), aa.x);
    kbs[s0 + 1] = fmaf(slope2, (float)(s0 + 1), aa.y);
    kbs[s0 + 2] = fmaf(slope2, (float)(s0 + 2), aa.z);
    kbs[s0 + 3] = fmaf(slope2, (float)(s0 + 3), aa.w);
    kbs[s0 + 4] = fmaf(slope2, (float)(s0 + 4), bb.x);
    kbs[s0 + 5] = fmaf(slope2, (float)(s0 + 5), bb.y);
    kbs[s0 + 6] = fmaf(slope2, (float)(s0 + 6), bb.z);
    kbs[s0 + 7] = fmaf(slope2, (float)(s0 + 7), bb.w);
  }

  // Q fragments (B-operand for swapped QK^T): lane holds Q[qt+m*16+lo][g*8..]
  uint4 aq[2][2];
#pragma unroll
  for (int m = 0; m < 2; ++m) {
    const u16* qp = Qb + (size_t)(b * S + qt + m * 16 + lo) * D + h * 64 + g * 8;
    aq[m][0] = *(const uint4*)qp;
    aq[m][1] = *(const uint4*)(qp + 32);
  }

  float mrow[2] = {-3.0e38f, -3.0e38f};
  float lrow[2] = {0.0f, 0.0f};
  f32x4 o[2][4] = {};   // o[m][dn]: O^T fragment, row d = dn*16+4g+j, col q = m*16+lo

  const u16* kbase = Kb + (size_t)b * S * D + h * 64;
  const u16* vbase = Vt + (size_t)(b * H + h) * 64 * S;

  // stage K/V tile kt into buf; source chunk XOR-swizzled: LDS(row,c)=G(row,c^row&7)
  auto stage = [&](int buf, int kt) {
#pragma unroll
    for (int j = 0; j < 2; ++j) {
      int i = j * 256 + tid;
      int row = i >> 3, c = i & 7;
      int sw = row & 7;
      u16* dK = &lK[buf][(j * 4 + w) * 512];
      u16* dV = &lV[buf][(j * 4 + w) * 512];
      gload_lds16(kbase + (size_t)(kt + row) * D + ((c ^ sw) * 8), dK);
      gload_lds16(vbase + (size_t)row * S + kt + ((c ^ sw) * 8), dV);
    }
  };

  __syncthreads();          // kbs ready
  stage(0, S - KV);         // prologue: highest-k tile first

#pragma unroll 1
  for (int tt = 0; tt < NT; ++tt) {
    const int buf = tt & 1;
    const int kt = (NT - 1 - tt) * KV;      // descending
    if (tt + 1 < NT) {
      stage(buf ^ 1, kt - KV);
      asm volatile("s_waitcnt vmcnt(4)" ::: "memory");   // stage(tt) landed
    } else {
      asm volatile("s_waitcnt vmcnt(0)" ::: "memory");
    }
    __builtin_amdgcn_s_barrier();
    __builtin_amdgcn_sched_barrier(0);

    const u16* lk = lK[buf];
    const u16* lv = lV[buf];

    // ---- swapped QK^T: sc[m][n] row=k-local(4g+j), col=q(lo) ----
    f32x4 sc[2][4];
    __builtin_amdgcn_s_setprio(1);
#pragma unroll
    for (int n = 0; n < 4; ++n) {
      int row = n * 16 + lo, sw = row & 7;
      uint4 k0 = *(const uint4*)&lk[row * 64 + ((g ^ sw) * 8)];
      uint4 k1 = *(const uint4*)&lk[row * 64 + (((g + 4) ^ sw) * 8)];
#pragma unroll
      for (int m = 0; m < 2; ++m) {
        f32x4 z4 = {0.f, 0.f, 0.f, 0.f};
        z4 = mfma_bf16(k0, aq[m][0], z4);
        sc[m][n] = mfma_bf16(k1, aq[m][1], z4);
      }
    }
    __builtin_amdgcn_s_setprio(0);

    // ---- bias: z = s*c1 + kbs[k], k = kt+16n+4g+j ----
#pragma unroll
    for (int n = 0; n < 4; ++n) {
      f32x4 kbv = *(const f32x4*)&kbs[kt + n * 16 + g * 4];
#pragma unroll
      for (int m = 0; m < 2; ++m)
#pragma unroll
        for (int j = 0; j < 4; ++j)
          sc[m][n][j] = fmaf(sc[m][n][j], c1, kbv[j]);
    }

    // ---- per-q-column tile max (in-lane tree + 2 shuffles) ----
    float pmv[2];
#pragma unroll
    for (int m = 0; m < 2; ++m) {
      f32x4 vm = sc[m][0];
#pragma unroll
      for (int n = 1; n < 4; ++n)
#pragma unroll
        for (int j = 0; j < 4; ++j) vm[j] = fmaxf(vm[j], sc[m][n][j]);
      float pm = fmaxf(fmaxf(vm[0], vm[1]), fmaxf(vm[2], vm[3]));
      pm = fmaxf(pm, __shfl_xor(pm, 16));
      pm = fmaxf(pm, __shfl_xor(pm, 32));
      pmv[m] = pm;
    }

    // ---- skip test: tile contributes < 64*2^-25 of row sum for ALL rows ----
    int keep = !((pmv[0] <= mrow[0] - 25.0f) && (pmv[1] <= mrow[1] - 25.0f));
    if (__any(keep)) {
      // ---- online softmax (full path) ----
#pragma unroll
      for (int m = 0; m < 2; ++m) {
        float mn = fmaxf(mrow[m], pmv[m]);
        float rs = exp2f(mrow[m] - mn);
        mrow[m] = mn;
        f32x4 vs = {0.f, 0.f, 0.f, 0.f};
#pragma unroll
        for (int n = 0; n < 4; ++n)
#pragma unroll
          for (int j = 0; j < 4; ++j) {
            float p = exp2f(sc[m][n][j] - mn);
            sc[m][n][j] = p;
            vs[j] += p;
          }
        float rsum = (vs[0] + vs[1]) + (vs[2] + vs[3]);
        rsum += __shfl_xor(rsum, 16);
        rsum += __shfl_xor(rsum, 32);
        lrow[m] = lrow[m] * rs + rsum;
#pragma unroll
        for (int dn = 0; dn < 4; ++dn)
#pragma unroll
          for (int j = 0; j < 4; ++j) o[m][dn][j] *= rs;
      }
      // ---- PV via k16 mfma: P lane-local; V from LDS (swizzled 8B reads) ----
      __builtin_amdgcn_s_setprio(1);
#pragma unroll
      for (int n = 0; n < 4; ++n) {
        uint2 pb0, pb1;
        pb0.x = pack2(sc[0][n][0], sc[0][n][1]);
        pb0.y = pack2(sc[0][n][2], sc[0][n][3]);
        pb1.x = pack2(sc[1][n][0], sc[1][n][1]);
        pb1.y = pack2(sc[1][n][2], sc[1][n][3]);
        int cw = 2 * n + (g >> 1);
        int off8 = (g & 1) * 4;
#pragma unroll
        for (int dn = 0; dn < 4; ++dn) {
          int row = dn * 16 + lo, sw = row & 7;
          uint2 va = *(const uint2*)&lv[row * 64 + ((cw ^ sw) * 8) + off8];
          o[0][dn] = mfma_bf16_k16(va, pb0, o[0][dn]);
          o[1][dn] = mfma_bf16_k16(va, pb1, o[1][dn]);
        }
      }
      __builtin_amdgcn_s_setprio(0);
    }

    __builtin_amdgcn_sched_barrier(0);
    __builtin_amdgcn_s_barrier();          // all waves done reading buf
  }

  // ---- normalize + store bf16 [B,S,H,hd]; ushort4 per (m,dn) ----
#pragma unroll
  for (int m = 0; m < 2; ++m) {
    float inv = 1.0f / fmaxf(lrow[m], 1e-30f);
    u16* orow = Ob + (size_t)(b * S + qt + m * 16 + lo) * D + h * 64 + g * 4;
#pragma unroll
    for (int dn = 0; dn < 4; ++dn) {
      ushort4 st;
      st.x = f2b_fast(o[m][dn][0] * inv);
      st.y = f2b_fast(o[m][dn][1] * inv);
      st.z = f2b_fast(o[m][dn][2] * inv);
      st.w = f2b_fast(o[m][dn][3] * inv);
      *(ushort4*)(orow + dn * 16) = st;
    }
  }
}

// ---------- host launcher ----------
extern "C" void kernel_launch(void* const* d_in, const int* in_sizes, int n_in,
                              void* d_out, int out_size, void* d_ws, size_t ws_size,
                              hipStream_t stream) {
  (void)in_sizes; (void)n_in; (void)out_size; (void)ws_size;
  const float* x  = (const float*)d_in[0];
  const float* Wq = (const float*)d_in[1];
  const float* bq = (const float*)d_in[2];
  const float* Wk = (const float*)d_in[3];
  const float* bk = (const float*)d_in[4];
  const float* Wv = (const float*)d_in[5];
  const float* bv = (const float*)d_in[6];
  const float* Wo = (const float*)d_in[7];
  const float* bo = (const float*)d_in[8];
  const int*  msk = (const int*)d_in[9];
  float* out = (float*)d_out;

  char* ws = (char*)d_ws;
  u16* xb  = (u16*)(ws);                       // 16MB; reused as attention output
  u16* Qb  = (u16*)(ws + ((size_t)16 << 20));
  u16* Kb  = (u16*)(ws + ((size_t)32 << 20));
  u16* Vt  = (u16*)(ws + ((size_t)48 << 20));
  u16* Wqb = (u16*)(ws + ((size_t)64 << 20));  // 4 weights, 2MB each
  float* mbf = (float*)(ws + ((size_t)72 << 20));  // mask bias, 32KB

  cast_x<<<4096, 256, 0, stream>>>(x, xb, 8192 * 1024);
  cast_w4<<<dim3(512, 4), 256, 0, stream>>>(Wq, Wk, Wv, Wo, Wqb);
  mask_bias<<<32, 256, 0, stream>>>(msk, mbf, 8192);

  gemm_qkv<<<dim3(24, 64), 256, 0, stream>>>(xb, Wqb, bq, bk, bv, Qb, Kb, Vt);

  attn_fa<<<dim3(16, 16, 4), 256, 0, stream>>>(Qb, Kb, Vt, mbf, xb /*Ob reuses xb*/);

  gemm_out<<<dim3(8, 64), 256, 0, stream>>>(xb, Wqb + (3u << 20), bo, out);
}

// Round 12
// 267.005 us; speedup vs baseline: 2.1261x; 1.1463x over previous
//
#include <hip/hip_runtime.h>
#include <hip/hip_bf16.h>

typedef unsigned short u16;
typedef __attribute__((ext_vector_type(8))) __bf16 bf16x8;
typedef __attribute__((ext_vector_type(4))) float f32x4;
typedef __attribute__((ext_vector_type(4))) short s16x4;

// ---------- helpers ----------
__device__ __forceinline__ u16 f2b(float f) {            // f32 -> bf16 RNE (manual)
  unsigned u = __builtin_bit_cast(unsigned, f);
  u = (u + 0x7fffu + ((u >> 16) & 1u)) >> 16;
  return (u16)u;
}

__device__ __forceinline__ u16 f2b_fast(float f) {       // native: enables v_cvt_pk_bf16_f32
  return __builtin_bit_cast(u16, (__bf16)f);
}

__device__ __forceinline__ unsigned pack2(float a, float b) {  // 2 f32 -> packed bf16x2
  return (unsigned)f2b_fast(a) | ((unsigned)f2b_fast(b) << 16);
}

__device__ __forceinline__ float blo(unsigned u) {       // low bf16 -> f32
  return __builtin_bit_cast(float, u << 16);
}
__device__ __forceinline__ float bhi(unsigned u) {       // high bf16 -> f32
  return __builtin_bit_cast(float, u & 0xffff0000u);
}

__device__ __forceinline__ f32x4 mfma_bf16(uint4 a, uint4 b, f32x4 c) {
  return __builtin_amdgcn_mfma_f32_16x16x32_bf16(
      __builtin_bit_cast(bf16x8, a), __builtin_bit_cast(bf16x8, b), c, 0, 0, 0);
}

// 16x16x16 bf16 MFMA: A/B = 2 VGPRs (4 bf16), C/D = 4 f32. B-frag k=(lane>>4)*4+e.
__device__ __forceinline__ f32x4 mfma_bf16_k16(uint2 a, uint2 b, f32x4 c) {
#if __has_builtin(__builtin_amdgcn_mfma_f32_16x16x16bf16_1k)
  return __builtin_amdgcn_mfma_f32_16x16x16bf16_1k(
      __builtin_bit_cast(s16x4, a), __builtin_bit_cast(s16x4, b), c, 0, 0, 0);
#elif __has_builtin(__builtin_amdgcn_mfma_f32_16x16x16_bf16)
  return __builtin_amdgcn_mfma_f32_16x16x16_bf16(
      __builtin_bit_cast(s16x4, a), __builtin_bit_cast(s16x4, b), c, 0, 0, 0);
#else
  f32x4 d;
  asm volatile("v_mfma_f32_16x16x16_bf16 %0, %1, %2, %3"
               : "=v"(d) : "v"(a), "v"(b), "v"(c));
  return d;
#endif
}

__device__ __forceinline__ void gload_lds16(const u16* g, u16* l) {
  __builtin_amdgcn_global_load_lds(
      (const __attribute__((address_space(1))) unsigned int*)(g),
      (__attribute__((address_space(3))) unsigned int*)(l), 16, 0, 0);
}

__device__ __forceinline__ void cast8(const float* __restrict__ s, u16* __restrict__ d) {
  float4 a = *(const float4*)s;
  float4 b = *(const float4*)(s + 4);
  ushort4 lo, hi;
  lo.x = f2b(a.x); lo.y = f2b(a.y); lo.z = f2b(a.z); lo.w = f2b(a.w);
  hi.x = f2b(b.x); hi.y = f2b(b.y); hi.z = f2b(b.z); hi.w = f2b(b.w);
  *(ushort4*)d = lo;
  *(ushort4*)(d + 4) = hi;
}

// ---------- cast kernels ----------
__global__ __launch_bounds__(256) void cast_x(const float* __restrict__ src,
                                              u16* __restrict__ dst, int n) {
  int i = (blockIdx.x * 256 + threadIdx.x) * 8;
  if (i + 8 <= n) cast8(src + i, dst + i);
}

__global__ __launch_bounds__(256) void cast_w4(const float* __restrict__ w0,
                                               const float* __restrict__ w1,
                                               const float* __restrict__ w2,
                                               const float* __restrict__ w3,
                                               u16* __restrict__ dst) {
  const float* s = (blockIdx.y == 0) ? w0 : (blockIdx.y == 1) ? w1
                 : (blockIdx.y == 2) ? w2 : w3;
  u16* d = dst + (size_t)blockIdx.y * (1u << 20);
  int i = (blockIdx.x * 256 + threadIdx.x) * 8;
  cast8(s + i, d + i);
}

// mask -> additive bias {0, -3e38}
__global__ __launch_bounds__(256) void mask_bias(const int* __restrict__ msk,
                                                 float* __restrict__ mb, int n) {
  int i = blockIdx.x * 256 + threadIdx.x;
  if (i < n) mb[i] = msk[i] ? 0.0f : -3.0e38f;
}

// per-(b,h,64-key-tile) max L2 norm of K rows (for Cauchy-Schwarz skip bound)
__global__ __launch_bounds__(256) void knorm(const u16* __restrict__ Kb,
                                             float* __restrict__ maxKt) {
  constexpr int S = 2048, D = 1024;
  __shared__ float nrm[128];
  const int t = threadIdx.x;
  const int b = blockIdx.z, h = blockIdx.y;
  const int r = blockIdx.x * 128 + (t >> 1);
  const u16* kp = Kb + (size_t)(b * S + r) * D + h * 64 + (t & 1) * 32;
  float ps = 0.f;
#pragma unroll
  for (int i = 0; i < 4; ++i) {
    uint4 u = *(const uint4*)(kp + i * 8);
    float f;
    f = blo(u.x); ps += f * f;  f = bhi(u.x); ps += f * f;
    f = blo(u.y); ps += f * f;  f = bhi(u.y); ps += f * f;
    f = blo(u.z); ps += f * f;  f = bhi(u.z); ps += f * f;
    f = blo(u.w); ps += f * f;  f = bhi(u.w); ps += f * f;
  }
  ps += __shfl_xor(ps, 1);
  if ((t & 1) == 0) nrm[t >> 1] = ps;
  __syncthreads();
  if (t < 2) {
    float m = 0.f;
#pragma unroll 8
    for (int i = 0; i < 64; ++i) m = fmaxf(m, nrm[t * 64 + i]);
    maxKt[((b * 16 + h) * 32) + blockIdx.x * 2 + t] = sqrtf(m);
  }
}

// ---------- fused QKV GEMM: 128x128 tiles, grid (24, 64) ----------
__global__ __launch_bounds__(256) void gemm_qkv(const u16* __restrict__ A,
                                                const u16* __restrict__ W,
                                                const float* __restrict__ bqp,
                                                const float* __restrict__ bkp,
                                                const float* __restrict__ bvp,
                                                u16* __restrict__ Qb,
                                                u16* __restrict__ Kb,
                                                u16* __restrict__ Vt) {
  constexpr int N = 1024, K = 1024;
  __shared__ u16 lA[128 * 32];
  __shared__ u16 lB[128 * 32];
  const int which = blockIdx.x >> 3;
  const int bx = blockIdx.x & 7;
  const u16* Bm = W + ((size_t)which << 20);
  const float* bias = (which == 0) ? bqp : (which == 1) ? bkp : bvp;

  const int tid = threadIdx.x;
  const int lane = tid & 63;
  const int w = tid >> 6;
  const int wr = w >> 1, wc = w & 1;
  const int rowBase = blockIdx.y * 128, colBase = bx * 128;
  const int lo = lane & 15, g = lane >> 4;

  f32x4 acc[4][4] = {};

  const int r0 = tid >> 2;
  const int c0 = (tid & 3) * 8;
  const u16* gA = A + (size_t)(rowBase + r0) * K + c0;
  const u16* gB = Bm + (size_t)(colBase + r0) * K + c0;
  u16* lAd = lA + w * 512;
  u16* lBd = lB + w * 512;

#pragma unroll 1
  for (int k0 = 0; k0 < K; k0 += 32) {
    gload_lds16(gA + k0, lAd);
    gload_lds16(gA + k0 + 64 * K, lAd + 2048);
    gload_lds16(gB + k0, lBd);
    gload_lds16(gB + k0 + 64 * K, lBd + 2048);
    __syncthreads();
    uint4 af[4], bf[4];
#pragma unroll
    for (int m = 0; m < 4; ++m)
      af[m] = *(const uint4*)&lA[(wr * 64 + m * 16 + lo) * 32 + g * 8];
#pragma unroll
    for (int n = 0; n < 4; ++n)
      bf[n] = *(const uint4*)&lB[(wc * 64 + n * 16 + lo) * 32 + g * 8];
#pragma unroll
    for (int m = 0; m < 4; ++m)
#pragma unroll
      for (int n = 0; n < 4; ++n)
        acc[m][n] = mfma_bf16(af[m], bf[n], acc[m][n]);
    __syncthreads();
  }

  const int cr = g * 4;
  if (which == 2) {  // V: transposed store -> Vt[b][h][hd][S]
#pragma unroll
    for (int m = 0; m < 4; ++m)
#pragma unroll
      for (int n = 0; n < 4; ++n) {
        int i0 = rowBase + wr * 64 + m * 16 + cr;
        int jf = colBase + wc * 64 + n * 16 + lo;
        float bv = bias[jf];
        int bb = i0 >> 11, s0 = i0 & 2047;
        int hh = jf >> 6, dd = jf & 63;
        ushort4 pk;
        pk.x = f2b(acc[m][n][0] + bv);
        pk.y = f2b(acc[m][n][1] + bv);
        pk.z = f2b(acc[m][n][2] + bv);
        pk.w = f2b(acc[m][n][3] + bv);
        *(ushort4*)(Vt + ((size_t)((bb * 16 + hh) * 64 + dd)) * 2048 + s0) = pk;
      }
  } else {
    u16* dst = which ? Kb : Qb;
#pragma unroll
    for (int m = 0; m < 4; ++m)
#pragma unroll
      for (int n = 0; n < 4; ++n) {
        int gr = rowBase + wr * 64 + m * 16 + cr;
        int gc = colBase + wc * 64 + n * 16 + lo;
        float bv = bias[gc];
#pragma unroll
        for (int j = 0; j < 4; ++j)
          dst[(size_t)(gr + j) * N + gc] = f2b(acc[m][n][j] + bv);
      }
  }
}

// ---------- O-projection GEMM (f32 out) ----------
__global__ __launch_bounds__(256) void gemm_out(const u16* __restrict__ A,
                                                const u16* __restrict__ Bm,
                                                const float* __restrict__ bias,
                                                float* __restrict__ Cout) {
  constexpr int N = 1024, K = 1024;
  __shared__ u16 lA[128 * 32];
  __shared__ u16 lB[128 * 32];
  const int tid = threadIdx.x;
  const int lane = tid & 63;
  const int w = tid >> 6;
  const int wr = w >> 1, wc = w & 1;
  const int rowBase = blockIdx.y * 128, colBase = blockIdx.x * 128;
  const int lo = lane & 15, g = lane >> 4;

  f32x4 acc[4][4] = {};
  const int r0 = tid >> 2;
  const int c0 = (tid & 3) * 8;
  const u16* gA = A + (size_t)(rowBase + r0) * K + c0;
  const u16* gB = Bm + (size_t)(colBase + r0) * K + c0;
  u16* lAd = lA + w * 512;
  u16* lBd = lB + w * 512;

#pragma unroll 1
  for (int k0 = 0; k0 < K; k0 += 32) {
    gload_lds16(gA + k0, lAd);
    gload_lds16(gA + k0 + 64 * K, lAd + 2048);
    gload_lds16(gB + k0, lBd);
    gload_lds16(gB + k0 + 64 * K, lBd + 2048);
    __syncthreads();
    uint4 af[4], bf[4];
#pragma unroll
    for (int m = 0; m < 4; ++m)
      af[m] = *(const uint4*)&lA[(wr * 64 + m * 16 + lo) * 32 + g * 8];
#pragma unroll
    for (int n = 0; n < 4; ++n)
      bf[n] = *(const uint4*)&lB[(wc * 64 + n * 16 + lo) * 32 + g * 8];
#pragma unroll
    for (int m = 0; m < 4; ++m)
#pragma unroll
      for (int n = 0; n < 4; ++n)
        acc[m][n] = mfma_bf16(af[m], bf[n], acc[m][n]);
    __syncthreads();
  }

  const int cr = g * 4;
#pragma unroll
  for (int m = 0; m < 4; ++m)
#pragma unroll
    for (int n = 0; n < 4; ++n) {
      int gr = rowBase + wr * 64 + m * 16 + cr;
      int gc = colBase + wc * 64 + n * 16 + lo;
      float bv = bias[gc];
#pragma unroll
      for (int j = 0; j < 4; ++j)
        Cout[(size_t)(gr + j) * N + gc] = acc[m][n][j] + bv;
    }
}

// ---------- flash attention: Cauchy-Schwarz pre-skip + LDS K/V + swapped QK^T ----
// Descending k-tiles. Pre-QK^T bound: score <= c1*|Q||K| + kbs[k] <=
// c1*Qmax*maxKt[t] + kbsmax[t]. If bound <= mrow_min - 25 for the wave,
// skip staging AND QK^T (contribution < 64*2^-25 of row sum). Block-uniform
// via LDS flag vote. Post-QK^T data-driven skip kept as backstop.
__global__ __launch_bounds__(256) void attn_fa(const u16* __restrict__ Qb,
                                               const u16* __restrict__ Kb,
                                               const u16* __restrict__ Vt,
                                               const float* __restrict__ mb,
                                               const float* __restrict__ maxKt,
                                               u16* __restrict__ Ob) {
  constexpr int S = 2048, D = 1024, H = 16, KV = 64, NT = S / KV;
  __shared__ float kbs[S];          // 8KB: ALiBi+mask bias (log2 domain)
  __shared__ float part[256];
  __shared__ float kbsmax[NT];
  __shared__ float mkt[NT];
  __shared__ int   flag[4];
  __shared__ u16 lK[64 * 64];       // 8KB: K tile, swizzled
  __shared__ u16 lV[64 * 64];       // 8KB: V^T tile, swizzled
  const int tid = threadIdx.x, lane = tid & 63, w = tid >> 6;
  const int lo = lane & 15, g = lane >> 4;
  const int b = blockIdx.z, h = blockIdx.y;
  const int qt = blockIdx.x * 128 + w * 32;
  const float LOG2E = 1.4426950408889634f;
  const float slope2 = exp2f(-(float)h / 16.0f) * LOG2E;  // slope * log2(e)
  const float c1 = 0.125f * LOG2E;                        // scale * log2(e)

  {  // kbs[s] = slope2*s + maskbias[s]; part[tid] = max of my 8 entries
    const float* mbb = mb + b * S;
    int s0 = tid * 8;
    float4 aa = *(const float4*)(mbb + s0);
    float4 bb = *(const float4*)(mbb + s0 + 4);
    float v0 = fmaf(slope2, (float)(s0 + 0), aa.x);
    float v1 = fmaf(slope2, (float)(s0 + 1), aa.y);
    float v2 = fmaf(slope2, (float)(s0 + 2), aa.z);
    float v3 = fmaf(slope2, (float)(s0 + 3), aa.w);
    float v4 = fmaf(slope2, (float)(s0 + 4), bb.x);
    float v5 = fmaf(slope2, (float)(s0 + 5), bb.y);
    float v6 = fmaf(slope2, (float)(s0 + 6), bb.z);
    float v7 = fmaf(slope2, (float)(s0 + 7), bb.w);
    kbs[s0 + 0] = v0; kbs[s0 + 1] = v1; kbs[s0 + 2] = v2; kbs[s0 + 3] = v3;
    kbs[s0 + 4] = v4; kbs[s0 + 5] = v5; kbs[s0 + 6] = v6; kbs[s0 + 7] = v7;
    float pm = fmaxf(fmaxf(fmaxf(v0, v1), fmaxf(v2, v3)),
                     fmaxf(fmaxf(v4, v5), fmaxf(v6, v7)));
    part[tid] = pm;
  }
  __syncthreads();
  if (tid < NT) {
    float m = part[tid * 8];
#pragma unroll
    for (int i = 1; i < 8; ++i) m = fmaxf(m, part[tid * 8 + i]);
    kbsmax[tid] = m;
    mkt[tid] = maxKt[((b * 16 + h) * 32) + tid];
  }

  // Q fragments (B-operand for swapped QK^T): lane holds Q[qt+m*16+lo][g*8..]
  uint4 aq[2][2];
#pragma unroll
  for (int m = 0; m < 2; ++m) {
    const u16* qp = Qb + (size_t)(b * S + qt + m * 16 + lo) * D + h * 64 + g * 8;
    aq[m][0] = *(const uint4*)qp;
    aq[m][1] = *(const uint4*)(qp + 32);
  }
  // Qmax over this wave's 32 rows (for the skip bound)
  float Qc;
  {
    float ps[2] = {0.f, 0.f};
#pragma unroll
    for (int m = 0; m < 2; ++m) {
      const uint* u = (const uint*)&aq[m][0];
#pragma unroll
      for (int i = 0; i < 8; ++i) {
        float f1 = blo(u[i]), f2 = bhi(u[i]);
        ps[m] += f1 * f1 + f2 * f2;
      }
    }
#pragma unroll
    for (int m = 0; m < 2; ++m) {
      ps[m] += __shfl_xor(ps[m], 16);
      ps[m] += __shfl_xor(ps[m], 32);
    }
    float qm = fmaxf(sqrtf(ps[0]), sqrtf(ps[1]));
    qm = fmaxf(qm, __shfl_xor(qm, 1));
    qm = fmaxf(qm, __shfl_xor(qm, 2));
    qm = fmaxf(qm, __shfl_xor(qm, 4));
    qm = fmaxf(qm, __shfl_xor(qm, 8));
    Qc = c1 * qm;
  }

  float mrow[2] = {-3.0e38f, -3.0e38f};
  float lrow[2] = {0.0f, 0.0f};
  float thr = -3.0e38f;   // mrow_min - 25
  f32x4 o[2][4] = {};

  const u16* kbase = Kb + (size_t)b * S * D + h * 64;
  const u16* vbase = Vt + (size_t)(b * H + h) * 64 * S;

  __syncthreads();          // kbsmax/mkt ready

#pragma unroll 1
  for (int tt = 0; tt < NT; ++tt) {
    const int tl = NT - 1 - tt;           // descending
    const int kt = tl * KV;
    // ---- pre-QK^T bound skip (wave-uniform) ----
    int keep_w = (fmaf(Qc, mkt[tl], kbsmax[tl]) > thr) ? 1 : 0;
    flag[w] = keep_w;
    __syncthreads();                      // flags visible
    int keep_blk = flag[0] | flag[1] | flag[2] | flag[3];
    if (keep_blk) {                       // stage K/V (block-uniform)
#pragma unroll
      for (int j = 0; j < 2; ++j) {
        int i = j * 256 + tid;
        int row = i >> 3, c = i & 7;
        int sw = row & 7;
        gload_lds16(kbase + (size_t)(kt + row) * D + ((c ^ sw) * 8),
                    &lK[(j * 4 + w) * 512]);
        gload_lds16(vbase + (size_t)row * S + kt + ((c ^ sw) * 8),
                    &lV[(j * 4 + w) * 512]);
      }
    }
    __syncthreads();                      // flags consumed + staging drained/visible
    if (keep_blk) {
      // ---- swapped QK^T: sc[m][n] row=k-local(4g+j), col=q(lo) ----
      f32x4 sc[2][4];
      __builtin_amdgcn_s_setprio(1);
#pragma unroll
      for (int n = 0; n < 4; ++n) {
        int row = n * 16 + lo, sw = row & 7;
        uint4 k0 = *(const uint4*)&lK[row * 64 + ((g ^ sw) * 8)];
        uint4 k1 = *(const uint4*)&lK[row * 64 + (((g + 4) ^ sw) * 8)];
#pragma unroll
        for (int m = 0; m < 2; ++m) {
          f32x4 z4 = {0.f, 0.f, 0.f, 0.f};
          z4 = mfma_bf16(k0, aq[m][0], z4);
          sc[m][n] = mfma_bf16(k1, aq[m][1], z4);
        }
      }
      __builtin_amdgcn_s_setprio(0);
      // ---- bias ----
#pragma unroll
      for (int n = 0; n < 4; ++n) {
        f32x4 kbv = *(const f32x4*)&kbs[kt + n * 16 + g * 4];
#pragma unroll
        for (int m = 0; m < 2; ++m)
#pragma unroll
          for (int j = 0; j < 4; ++j)
            sc[m][n][j] = fmaf(sc[m][n][j], c1, kbv[j]);
      }
      // ---- per-q-column tile max ----
      float pmv[2];
#pragma unroll
      for (int m = 0; m < 2; ++m) {
        f32x4 vm = sc[m][0];
#pragma unroll
        for (int n = 1; n < 4; ++n)
#pragma unroll
          for (int j = 0; j < 4; ++j) vm[j] = fmaxf(vm[j], sc[m][n][j]);
        float pm = fmaxf(fmaxf(vm[0], vm[1]), fmaxf(vm[2], vm[3]));
        pm = fmaxf(pm, __shfl_xor(pm, 16));
        pm = fmaxf(pm, __shfl_xor(pm, 32));
        pmv[m] = pm;
      }
      // ---- backstop data-driven skip ----
      int keep2 = !((pmv[0] <= mrow[0] - 25.0f) && (pmv[1] <= mrow[1] - 25.0f));
      if (__any(keep2)) {
#pragma unroll
        for (int m = 0; m < 2; ++m) {
          float mn = fmaxf(mrow[m], pmv[m]);
          float rs = exp2f(mrow[m] - mn);
          mrow[m] = mn;
          f32x4 vs = {0.f, 0.f, 0.f, 0.f};
#pragma unroll
          for (int n = 0; n < 4; ++n)
#pragma unroll
            for (int j = 0; j < 4; ++j) {
              float p = exp2f(sc[m][n][j] - mn);
              sc[m][n][j] = p;
              vs[j] += p;
            }
          float rsum = (vs[0] + vs[1]) + (vs[2] + vs[3]);
          rsum += __shfl_xor(rsum, 16);
          rsum += __shfl_xor(rsum, 32);
          lrow[m] = lrow[m] * rs + rsum;
#pragma unroll
          for (int dn = 0; dn < 4; ++dn)
#pragma unroll
            for (int j = 0; j < 4; ++j) o[m][dn][j] *= rs;
        }
        // ---- PV via k16 mfma ----
        __builtin_amdgcn_s_setprio(1);
#pragma unroll
        for (int n = 0; n < 4; ++n) {
          uint2 pb0, pb1;
          pb0.x = pack2(sc[0][n][0], sc[0][n][1]);
          pb0.y = pack2(sc[0][n][2], sc[0][n][3]);
          pb1.x = pack2(sc[1][n][0], sc[1][n][1]);
          pb1.y = pack2(sc[1][n][2], sc[1][n][3]);
          int cw = 2 * n + (g >> 1);
          int off8 = (g & 1) * 4;
#pragma unroll
          for (int dn = 0; dn < 4; ++dn) {
            int row = dn * 16 + lo, sw = row & 7;
            uint2 va = *(const uint2*)&lV[row * 64 + ((cw ^ sw) * 8) + off8];
            o[0][dn] = mfma_bf16_k16(va, pb0, o[0][dn]);
            o[1][dn] = mfma_bf16_k16(va, pb1, o[1][dn]);
          }
        }
        __builtin_amdgcn_s_setprio(0);
        // ---- update skip threshold: wave-min running max ----
        float mm = fminf(mrow[0], mrow[1]);
        mm = fminf(mm, __shfl_xor(mm, 1));
        mm = fminf(mm, __shfl_xor(mm, 2));
        mm = fminf(mm, __shfl_xor(mm, 4));
        mm = fminf(mm, __shfl_xor(mm, 8));
        thr = mm - 25.0f;
      }
      __syncthreads();                    // LDS tiles consumed before next stage
    }
  }

  // ---- normalize + store bf16 [B,S,H,hd]; ushort4 per (m,dn) ----
#pragma unroll
  for (int m = 0; m < 2; ++m) {
    float inv = 1.0f / fmaxf(lrow[m], 1e-30f);
    u16* orow = Ob + (size_t)(b * S + qt + m * 16 + lo) * D + h * 64 + g * 4;
#pragma unroll
    for (int dn = 0; dn < 4; ++dn) {
      ushort4 st;
      st.x = f2b_fast(o[m][dn][0] * inv);
      st.y = f2b_fast(o[m][dn][1] * inv);
      st.z = f2b_fast(o[m][dn][2] * inv);
      st.w = f2b_fast(o[m][dn][3] * inv);
      *(ushort4*)(orow + dn * 16) = st;
    }
  }
}

// ---------- host launcher ----------
extern "C" void kernel_launch(void* const* d_in, const int* in_sizes, int n_in,
                              void* d_out, int out_size, void* d_ws, size_t ws_size,
                              hipStream_t stream) {
  (void)in_sizes; (void)n_in; (void)out_size; (void)ws_size;
  const float* x  = (const float*)d_in[0];
  const float* Wq = (const float*)d_in[1];
  const float* bq = (const float*)d_in[2];
  const float* Wk = (const float*)d_in[3];
  const float* bk = (const float*)d_in[4];
  const float* Wv = (const float*)d_in[5];
  const float* bv = (const float*)d_in[6];
  const float* Wo = (const float*)d_in[7];
  const float* bo = (const float*)d_in[8];
  const int*  msk = (const int*)d_in[9];
  float* out = (float*)d_out;

  char* ws = (char*)d_ws;
  u16* xb  = (u16*)(ws);                       // 16MB; reused as attention output
  u16* Qb  = (u16*)(ws + ((size_t)16 << 20));
  u16* Kb  = (u16*)(ws + ((size_t)32 << 20));
  u16* Vt  = (u16*)(ws + ((size_t)48 << 20));
  u16* Wqb = (u16*)(ws + ((size_t)64 << 20));  // 4 weights, 2MB each
  float* mbf  = (float*)(ws + ((size_t)72 << 20));           // mask bias, 32KB
  float* mKt  = (float*)(ws + ((size_t)72 << 20) + 65536);   // maxKt, 8KB

  cast_x<<<4096, 256, 0, stream>>>(x, xb, 8192 * 1024);
  cast_w4<<<dim3(512, 4), 256, 0, stream>>>(Wq, Wk, Wv, Wo, Wqb);
  mask_bias<<<32, 256, 0, stream>>>(msk, mbf, 8192);

  gemm_qkv<<<dim3(24, 64), 256, 0, stream>>>(xb, Wqb, bq, bk, bv, Qb, Kb, Vt);

  knorm<<<dim3(16, 16, 4), 256, 0, stream>>>(Kb, mKt);

  attn_fa<<<dim3(16, 16, 4), 256, 0, stream>>>(Qb, Kb, Vt, mbf, mKt, xb);

  gemm_out<<<dim3(8, 64), 256, 0, stream>>>(xb, Wqb + (3u << 20), bo, out);
}